// Round 4
// baseline (36.011 us; speedup 1.0000x reference)
//
#include <hip/hip_runtime.h>
#include <math.h>

#define DQ    512        // input feature dim
#define NQ    4          // qubits
#define LQ    2          // layers
#define RPB   32         // rows per block
#define BLOCK 256
#define WAVES 4
#define RPW   8          // rows per wave

// Sum across each 16-lane DPP row (pure VALU, 4 ops).
__device__ __forceinline__ float rowsum16(float v) {
    int x;
    x = __builtin_amdgcn_update_dpp(0, __float_as_int(v), 0x121, 0xF, 0xF, true); // ror:1
    v += __int_as_float(x);
    x = __builtin_amdgcn_update_dpp(0, __float_as_int(v), 0x122, 0xF, 0xF, true); // ror:2
    v += __int_as_float(x);
    x = __builtin_amdgcn_update_dpp(0, __float_as_int(v), 0x124, 0xF, 0xF, true); // ror:4
    v += __int_as_float(x);
    x = __builtin_amdgcn_update_dpp(0, __float_as_int(v), 0x128, 0xF, 0xF, true); // ror:8
    v += __int_as_float(x);
    return v;
}

__device__ __forceinline__ float fast_tanh(float x) {
    const float e = __expf(2.0f * x);
    return 1.0f - 2.0f / (e + 1.0f);   // robust: e=inf -> 1, e=0 -> -1
}

__global__ __launch_bounds__(BLOCK, 4) void qrnn_kernel(
    const float* __restrict__ inputs,   // (B,512)
    const float* __restrict__ prev_h,   // (B,4)
    const float* __restrict__ W_enc,    // (516,4)
    const float* __restrict__ b_enc,    // (4)
    const float* __restrict__ theta,    // (2,4,3)
    const float* __restrict__ W_out,    // (4,4)
    const float* __restrict__ b_out,    // (4)
    float* __restrict__ out,            // (B,4)
    int B)
{
    // All LDS is wave-private regions -> NO __syncthreads anywhere.
    __shared__ float4 sPart[RPB][5];        // 4 group-partials per row, stride 20 floats
    __shared__ float  sC[RPB * 5];          // cos(half-angle), stride 5
    __shared__ float  sS[RPB * 5];          // sin(half-angle)
    __shared__ float  sU[WAVES][LQ * NQ * 8]; // unitaries, replicated per wave

    const int tid  = threadIdx.x;
    const int lane = tid & 63;
    const int wave = tid >> 6;
    const int blockBase = blockIdx.x * RPB;
    const int rbase = wave * RPW;

    const float4* __restrict__ W4  = (const float4*)W_enc;
    const float4* __restrict__ in4 = (const float4*)inputs;

    // ---- Issue the first global loads ASAP (4 rows in flight) ----
    float4 xb[4][2];
#pragma unroll
    for (int p = 0; p < 4; ++p) {
        const size_t rowOff = (size_t)(blockBase + rbase + p) * (DQ / 4);
        xb[p][0] = in4[rowOff + lane];
        xb[p][1] = in4[rowOff + lane + 64];
    }

    // ---- Phase 0 (per wave, lanes 0-7): unitaries U = RY * RZ * RX ----
    if (lane < LQ * NQ) {
        const int l = lane >> 2, q = lane & 3;
        const float a  = theta[(l * NQ + q) * 3 + 0] * 0.5f;
        const float b  = theta[(l * NQ + q) * 3 + 1] * 0.5f;
        const float cc = theta[(l * NQ + q) * 3 + 2] * 0.5f;
        float sa, ca, sb, cb, sy, cy;
        __sincosf(a,  &sa, &ca);
        __sincosf(b,  &sb, &cb);
        __sincosf(cc, &sy, &cy);
        const float m00r =  ca * cb, m00i = -ca * sb;
        const float m01r = -sa * sb, m01i = -sa * cb;
        const float m10r =  sa * sb, m10i = -sa * cb;
        const float m11r =  ca * cb, m11i =  ca * sb;
        float* u = &sU[wave][lane * 8];
        u[0] = cy * m00r - sy * m10r;  u[1] = cy * m00i - sy * m10i;  // U00
        u[2] = cy * m01r - sy * m11r;  u[3] = cy * m01i - sy * m11i;  // U01
        u[4] = sy * m00r + cy * m10r;  u[5] = sy * m00i + cy * m10i;  // U10
        u[6] = sy * m01r + cy * m11r;  u[7] = sy * m01i + cy * m11i;  // U11
    }

    // ---- Weight registers: lane owns features 4*lane..+3 and 256+4*lane..+3 ----
    float4 wreg[8];
#pragma unroll
    for (int k = 0; k < 4; ++k) {
        wreg[k]     = W4[4 * lane + k];
        wreg[k + 4] = W4[256 + 4 * lane + k];
    }

    // ---- Phase 1a: one row per wave-iteration, 4-deep load pipeline ----
#pragma unroll
    for (int r = 0; r < RPW; ++r) {
        const int slot = r & 3;
        const float4 x0 = xb[slot][0];
        const float4 x1 = xb[slot][1];
        if (r + 4 < RPW) {
            const size_t rowOff = (size_t)(blockBase + rbase + r + 4) * (DQ / 4);
            xb[slot][0] = in4[rowOff + lane];
            xb[slot][1] = in4[rowOff + lane + 64];
        }

        const float xs[8] = { x0.x, x0.y, x0.z, x0.w, x1.x, x1.y, x1.z, x1.w };
        float4 acc = make_float4(0.f, 0.f, 0.f, 0.f);
#pragma unroll
        for (int k = 0; k < 8; ++k) {
            acc.x += xs[k] * wreg[k].x;
            acc.y += xs[k] * wreg[k].y;
            acc.z += xs[k] * wreg[k].z;
            acc.w += xs[k] * wreg[k].w;
        }
        acc.x = rowsum16(acc.x);
        acc.y = rowsum16(acc.y);
        acc.z = rowsum16(acc.z);
        acc.w = rowsum16(acc.w);
        if ((lane & 15) == 0) sPart[rbase + r][lane >> 4] = acc;
    }

    // ---- Phase 1b (per wave, lanes 0-31): finish dot, prev_h, bias, tanh, sincos ----
    // lane -> (row = rbase + lane>>2, comp = lane&3); sPart written by this wave.
    if (lane < 32) {
        const int rl   = rbase + (lane >> 2);
        const int comp = lane & 3;
        const float* pp = (const float*)&sPart[rl][0];
        float s = pp[comp] + pp[4 + comp] + pp[8 + comp] + pp[12 + comp];

        const float4 ph = *(const float4*)(prev_h + (size_t)(blockBase + rl) * 4);
        s += ph.x * W_enc[512 * 4 + comp];
        s += ph.y * W_enc[513 * 4 + comp];
        s += ph.z * W_enc[514 * 4 + comp];
        s += ph.w * W_enc[515 * 4 + comp];
        s += b_enc[comp];

        const float h = fast_tanh(s) * 1.57079632679489662f;   // half-angle
        float sn, cs;
        __sincosf(h, &sn, &cs);
        sC[rl * 5 + comp] = cs;
        sS[rl * 5 + comp] = sn;
    }

    // ---- Phase 2 (per wave, lanes 0-7): 16-amplitude circuit, one row per lane ----
    if (lane < RPW) {
        const int rl  = rbase + lane;
        const int row = blockBase + rl;
        float cq[4], sq[4];
#pragma unroll
        for (int j = 0; j < 4; ++j) {
            cq[j] = sC[rl * 5 + j];
            sq[j] = sS[rl * 5 + j];
        }

        float ar[16], ai[16];
#pragma unroll
        for (int j = 0; j < 16; ++j) {
            float v = ((j >> 3) & 1) ? sq[0] : cq[0];
            v      *= ((j >> 2) & 1) ? sq[1] : cq[1];
            v      *= ((j >> 1) & 1) ? sq[2] : cq[2];
            v      *= ((j >> 0) & 1) ? sq[3] : cq[3];
            ar[j] = v;
            ai[j] = 0.f;
        }

        const float* uw = &sU[wave][0];
#pragma unroll
        for (int l = 0; l < LQ; ++l) {
#pragma unroll
            for (int q = 0; q < NQ; ++q) {
                const float* u = &uw[(l * NQ + q) * 8];
                const float u00r = u[0], u00i = u[1], u01r = u[2], u01i = u[3];
                const float u10r = u[4], u10i = u[5], u11r = u[6], u11i = u[7];
                const int bit = 1 << (3 - q);
#pragma unroll
                for (int j = 0; j < 16; ++j) {
                    if (j & bit) continue;          // compile-time resolved
                    const int k = j | bit;
                    const float a0r = ar[j], a0i = ai[j];
                    const float a1r = ar[k], a1i = ai[k];
                    ar[j] = u00r * a0r - u00i * a0i + u01r * a1r - u01i * a1i;
                    ai[j] = u00r * a0i + u00i * a0r + u01r * a1i + u01i * a1r;
                    ar[k] = u10r * a0r - u10i * a0i + u11r * a1r - u11i * a1i;
                    ai[k] = u10r * a0i + u10i * a0r + u11r * a1i + u11i * a1r;
                }
            }
#pragma unroll
            for (int q = 0; q < NQ - 1; ++q) {      // CNOT chain
                const int cb = 1 << (3 - q), tb = 1 << (2 - q);
#pragma unroll
                for (int j = 0; j < 16; ++j) {
                    if ((j & cb) && !(j & tb)) {    // compile-time resolved
                        const int k = j | tb;
                        float t;
                        t = ar[j]; ar[j] = ar[k]; ar[k] = t;
                        t = ai[j]; ai[j] = ai[k]; ai[k] = t;
                    }
                }
            }
        }

        // PauliZ expectations
        float ev[4] = { 0.f, 0.f, 0.f, 0.f };
#pragma unroll
        for (int j = 0; j < 16; ++j) {
            const float p = ar[j] * ar[j] + ai[j] * ai[j];
#pragma unroll
            for (int q = 0; q < 4; ++q)
                ev[q] += (j & (1 << (3 - q))) ? -p : p;
        }

        // output layer
        float ob[4];
#pragma unroll
        for (int j = 0; j < 4; ++j) {
            float t = b_out[j];
#pragma unroll
            for (int q = 0; q < 4; ++q) t += ev[q] * W_out[q * 4 + j];
            ob[j] = fast_tanh(t);
        }
        *(float4*)(out + (size_t)row * 4) = make_float4(ob[0], ob[1], ob[2], ob[3]);
    }
}

extern "C" void kernel_launch(void* const* d_in, const int* in_sizes, int n_in,
                              void* d_out, int out_size, void* d_ws, size_t ws_size,
                              hipStream_t stream) {
    const float* inputs = (const float*)d_in[0];
    const float* prev_h = (const float*)d_in[1];
    const float* W_enc  = (const float*)d_in[2];
    const float* b_enc  = (const float*)d_in[3];
    const float* theta  = (const float*)d_in[4];
    const float* W_out  = (const float*)d_in[5];
    const float* b_out  = (const float*)d_in[6];
    float* out = (float*)d_out;

    const int B = in_sizes[0] / DQ;                 // 32768
    const int grid = (B + RPB - 1) / RPB;           // 1024

    qrnn_kernel<<<grid, BLOCK, 0, stream>>>(inputs, prev_h, W_enc, b_enc, theta,
                                            W_out, b_out, out, B);
}

// Round 5
// 22.529 us; speedup vs baseline: 1.5984x; 1.5984x over previous
//
#include <hip/hip_runtime.h>
#include <math.h>

#define DQ    512        // input feature dim
#define NQ    4          // qubits
#define LQ    2          // layers
#define RPB   32         // rows per block (K1)
#define BLOCK 256
#define RPW   8          // rows per wave (K1)

// Sum across each 16-lane DPP row (pure VALU, 8 ops, chain ~4 deep x2).
__device__ __forceinline__ float rowsum16(float v) {
    int x;
    x = __builtin_amdgcn_update_dpp(0, __float_as_int(v), 0x121, 0xF, 0xF, true); // ror:1
    v += __int_as_float(x);
    x = __builtin_amdgcn_update_dpp(0, __float_as_int(v), 0x122, 0xF, 0xF, true); // ror:2
    v += __int_as_float(x);
    x = __builtin_amdgcn_update_dpp(0, __float_as_int(v), 0x124, 0xF, 0xF, true); // ror:4
    v += __int_as_float(x);
    x = __builtin_amdgcn_update_dpp(0, __float_as_int(v), 0x128, 0xF, 0xF, true); // ror:8
    v += __int_as_float(x);
    return v;
}

__device__ __forceinline__ float fast_tanh(float x) {
    const float e = __expf(2.0f * x);
    return 1.0f - 2.0f / (e + 1.0f);   // robust: e=inf -> 1, e=0 -> -1
}

// ================= K1: streaming encode (GEMV + tanh + sincos) =================
// Lean waves: ~90 VGPR, no circuit code. Writes (cos4, sin4) per row to ws.
__global__ __launch_bounds__(BLOCK, 4) void qrnn_encode(
    const float* __restrict__ inputs,   // (B,512)
    const float* __restrict__ prev_h,   // (B,4)
    const float* __restrict__ W_enc,    // (516,4)
    const float* __restrict__ b_enc,    // (4)
    float* __restrict__ ws,             // (B,8): cos[0..3], sin[0..3]
    int B)
{
    __shared__ float4 sPart[RPB][5];        // 4 group-partials per row, stride 20 floats

    const int tid  = threadIdx.x;
    const int lane = tid & 63;
    const int wave = tid >> 6;
    const int blockBase = blockIdx.x * RPB;
    const int rbase = wave * RPW;

    const float4* __restrict__ W4  = (const float4*)W_enc;
    const float4* __restrict__ in4 = (const float4*)inputs;

    // issue first loads ASAP: 4 rows in flight (8 KB/wave)
    float4 xb[4][2];
#pragma unroll
    for (int p = 0; p < 4; ++p) {
        const size_t rowOff = (size_t)(blockBase + rbase + p) * (DQ / 4);
        xb[p][0] = in4[rowOff + lane];
        xb[p][1] = in4[rowOff + lane + 64];
    }

    // weights: lane owns features 4*lane..+3 and 256+4*lane..+3
    float4 wreg[8];
#pragma unroll
    for (int k = 0; k < 4; ++k) {
        wreg[k]     = W4[4 * lane + k];
        wreg[k + 4] = W4[256 + 4 * lane + k];
    }

#pragma unroll
    for (int r = 0; r < RPW; ++r) {
        const int slot = r & 3;
        const float4 x0 = xb[slot][0];
        const float4 x1 = xb[slot][1];
        if (r + 4 < RPW) {
            const size_t rowOff = (size_t)(blockBase + rbase + r + 4) * (DQ / 4);
            xb[slot][0] = in4[rowOff + lane];
            xb[slot][1] = in4[rowOff + lane + 64];
        }

        const float xs[8] = { x0.x, x0.y, x0.z, x0.w, x1.x, x1.y, x1.z, x1.w };
        float4 acc = make_float4(0.f, 0.f, 0.f, 0.f);
#pragma unroll
        for (int k = 0; k < 8; ++k) {
            acc.x += xs[k] * wreg[k].x;
            acc.y += xs[k] * wreg[k].y;
            acc.z += xs[k] * wreg[k].z;
            acc.w += xs[k] * wreg[k].w;
        }
        acc.x = rowsum16(acc.x);
        acc.y = rowsum16(acc.y);
        acc.z = rowsum16(acc.z);
        acc.w = rowsum16(acc.w);
        if ((lane & 15) == 0) sPart[rbase + r][lane >> 4] = acc;
    }

    __syncthreads();

    // finish: thread -> (row = t>>2, comp = t&3); 128 active threads
    if (tid < RPB * 4) {
        const int row  = tid >> 2;
        const int comp = tid & 3;
        const float* pp = (const float*)&sPart[row][0];
        float s = pp[comp] + pp[4 + comp] + pp[8 + comp] + pp[12 + comp];

        const int grow = blockBase + row;
        const float4 ph = *(const float4*)(prev_h + (size_t)grow * 4);
        s += ph.x * W_enc[512 * 4 + comp];
        s += ph.y * W_enc[513 * 4 + comp];
        s += ph.z * W_enc[514 * 4 + comp];
        s += ph.w * W_enc[515 * 4 + comp];
        s += b_enc[comp];

        const float h = fast_tanh(s) * 1.57079632679489662f;   // half-angle
        float sn, cs;
        __sincosf(h, &sn, &cs);
        ws[(size_t)grow * 8 + comp]     = cs;
        ws[(size_t)grow * 8 + 4 + comp] = sn;
    }
}

// ================= K2: per-row quantum circuit (1 thread per row) =================
__global__ __launch_bounds__(BLOCK) void qrnn_circuit(
    const float* __restrict__ ws,       // (B,8): cos4, sin4
    const float* __restrict__ theta,    // (2,4,3)
    const float* __restrict__ W_out,    // (4,4)
    const float* __restrict__ b_out,    // (4)
    float* __restrict__ out,            // (B,4)
    int B)
{
    __shared__ float sU[LQ * NQ * 8];   // 8 unitaries, 2x2 complex each

    const int tid = threadIdx.x;
    if (tid < LQ * NQ) {
        const int l = tid >> 2, q = tid & 3;
        const float a  = theta[(l * NQ + q) * 3 + 0] * 0.5f;
        const float b  = theta[(l * NQ + q) * 3 + 1] * 0.5f;
        const float cc = theta[(l * NQ + q) * 3 + 2] * 0.5f;
        float sa, ca, sb, cb, sy, cy;
        __sincosf(a,  &sa, &ca);
        __sincosf(b,  &sb, &cb);
        __sincosf(cc, &sy, &cy);
        const float m00r =  ca * cb, m00i = -ca * sb;
        const float m01r = -sa * sb, m01i = -sa * cb;
        const float m10r =  sa * sb, m10i = -sa * cb;
        const float m11r =  ca * cb, m11i =  ca * sb;
        float* u = &sU[tid * 8];
        u[0] = cy * m00r - sy * m10r;  u[1] = cy * m00i - sy * m10i;  // U00
        u[2] = cy * m01r - sy * m11r;  u[3] = cy * m01i - sy * m11i;  // U01
        u[4] = sy * m00r + cy * m10r;  u[5] = sy * m00i + cy * m10i;  // U10
        u[6] = sy * m01r + cy * m11r;  u[7] = sy * m01i + cy * m11i;  // U11
    }
    __syncthreads();

    const int row = blockIdx.x * BLOCK + tid;
    if (row >= B) return;

    const float4 c4 = ((const float4*)ws)[(size_t)row * 2];
    const float4 s4 = ((const float4*)ws)[(size_t)row * 2 + 1];
    const float cq[4] = { c4.x, c4.y, c4.z, c4.w };
    const float sq[4] = { s4.x, s4.y, s4.z, s4.w };

    float ar[16], ai[16];
#pragma unroll
    for (int j = 0; j < 16; ++j) {
        float v = ((j >> 3) & 1) ? sq[0] : cq[0];
        v      *= ((j >> 2) & 1) ? sq[1] : cq[1];
        v      *= ((j >> 1) & 1) ? sq[2] : cq[2];
        v      *= ((j >> 0) & 1) ? sq[3] : cq[3];
        ar[j] = v;
        ai[j] = 0.f;
    }

#pragma unroll
    for (int l = 0; l < LQ; ++l) {
#pragma unroll
        for (int q = 0; q < NQ; ++q) {
            const float* u = &sU[(l * NQ + q) * 8];
            const float u00r = u[0], u00i = u[1], u01r = u[2], u01i = u[3];
            const float u10r = u[4], u10i = u[5], u11r = u[6], u11i = u[7];
            const int bit = 1 << (3 - q);
#pragma unroll
            for (int j = 0; j < 16; ++j) {
                if (j & bit) continue;          // compile-time resolved
                const int k = j | bit;
                const float a0r = ar[j], a0i = ai[j];
                const float a1r = ar[k], a1i = ai[k];
                ar[j] = u00r * a0r - u00i * a0i + u01r * a1r - u01i * a1i;
                ai[j] = u00r * a0i + u00i * a0r + u01r * a1i + u01i * a1r;
                ar[k] = u10r * a0r - u10i * a0i + u11r * a1r - u11i * a1i;
                ai[k] = u10r * a0i + u10i * a0r + u11r * a1i + u11i * a1r;
            }
        }
#pragma unroll
        for (int q = 0; q < NQ - 1; ++q) {      // CNOT chain
            const int cb = 1 << (3 - q), tb = 1 << (2 - q);
#pragma unroll
            for (int j = 0; j < 16; ++j) {
                if ((j & cb) && !(j & tb)) {    // compile-time resolved
                    const int k = j | tb;
                    float t;
                    t = ar[j]; ar[j] = ar[k]; ar[k] = t;
                    t = ai[j]; ai[j] = ai[k]; ai[k] = t;
                }
            }
        }
    }

    // PauliZ expectations
    float ev[4] = { 0.f, 0.f, 0.f, 0.f };
#pragma unroll
    for (int j = 0; j < 16; ++j) {
        const float p = ar[j] * ar[j] + ai[j] * ai[j];
#pragma unroll
        for (int q = 0; q < 4; ++q)
            ev[q] += (j & (1 << (3 - q))) ? -p : p;
    }

    // output layer
    float ob[4];
#pragma unroll
    for (int j = 0; j < 4; ++j) {
        float t = b_out[j];
#pragma unroll
        for (int q = 0; q < 4; ++q) t += ev[q] * W_out[q * 4 + j];
        ob[j] = fast_tanh(t);
    }
    *(float4*)(out + (size_t)row * 4) = make_float4(ob[0], ob[1], ob[2], ob[3]);
}

extern "C" void kernel_launch(void* const* d_in, const int* in_sizes, int n_in,
                              void* d_out, int out_size, void* d_ws, size_t ws_size,
                              hipStream_t stream) {
    const float* inputs = (const float*)d_in[0];
    const float* prev_h = (const float*)d_in[1];
    const float* W_enc  = (const float*)d_in[2];
    const float* b_enc  = (const float*)d_in[3];
    const float* theta  = (const float*)d_in[4];
    const float* W_out  = (const float*)d_in[5];
    const float* b_out  = (const float*)d_in[6];
    float* out = (float*)d_out;
    float* ws  = (float*)d_ws;                      // B*8 floats = 1 MB

    const int B = in_sizes[0] / DQ;                 // 32768
    const int grid1 = (B + RPB - 1) / RPB;          // 1024
    const int grid2 = (B + BLOCK - 1) / BLOCK;      // 128

    qrnn_encode<<<grid1, BLOCK, 0, stream>>>(inputs, prev_h, W_enc, b_enc, ws, B);
    qrnn_circuit<<<grid2, BLOCK, 0, stream>>>(ws, theta, W_out, b_out, out, B);
}

// Round 6
// 22.003 us; speedup vs baseline: 1.6367x; 1.0239x over previous
//
#include <hip/hip_runtime.h>
#include <math.h>

#define DQ    512        // input feature dim
#define NQ    4          // qubits
#define LQ    2          // layers
#define RPB   64         // rows per block
#define BLOCK 256
#define RPW   16         // rows per wave

// Sum across each 16-lane DPP row (pure VALU).
__device__ __forceinline__ float rowsum16(float v) {
    int x;
    x = __builtin_amdgcn_update_dpp(0, __float_as_int(v), 0x121, 0xF, 0xF, true); // ror:1
    v += __int_as_float(x);
    x = __builtin_amdgcn_update_dpp(0, __float_as_int(v), 0x122, 0xF, 0xF, true); // ror:2
    v += __int_as_float(x);
    x = __builtin_amdgcn_update_dpp(0, __float_as_int(v), 0x124, 0xF, 0xF, true); // ror:4
    v += __int_as_float(x);
    x = __builtin_amdgcn_update_dpp(0, __float_as_int(v), 0x128, 0xF, 0xF, true); // ror:8
    v += __int_as_float(x);
    return v;
}

__device__ __forceinline__ float fast_tanh(float x) {
    const float e = __expf(2.0f * x);
    return 1.0f - 2.0f / (e + 1.0f);   // robust: e=inf -> 1, e=0 -> -1
}

__global__ __launch_bounds__(BLOCK) void qrnn_kernel(
    const float* __restrict__ inputs,   // (B,512)
    const float* __restrict__ prev_h,   // (B,4)
    const float* __restrict__ W_enc,    // (516,4)
    const float* __restrict__ b_enc,    // (4)
    const float* __restrict__ theta,    // (2,4,3)
    const float* __restrict__ W_out,    // (4,4)
    const float* __restrict__ b_out,    // (4)
    float* __restrict__ out,            // (B,4)
    int B)
{
    __shared__ float4 sPart[RPB][5];       // 4 group-partials per row (stride 20 dwords)
    __shared__ float  sU[LQ * NQ * 8];     // 8 unitaries, 2x2 complex (wave-0 private)

    const int tid  = threadIdx.x;
    const int lane = tid & 63;
    const int wave = tid >> 6;
    const int blockBase = blockIdx.x * RPB;
    const int r0 = wave * RPW;

    const float4* __restrict__ W4  = (const float4*)W_enc;
    const float4* __restrict__ in4 = (const float4*)inputs;

    // ---- Issue input prefetch FIRST (critical path): 4 rows in flight ----
    float4 xb[4][2];
#pragma unroll
    for (int p = 0; p < 4; ++p) {
        const size_t rowOff = (size_t)(blockBase + r0 + p) * (DQ / 4);
        xb[p][0] = in4[rowOff + lane];
        xb[p][1] = in4[rowOff + lane + 64];
    }

    // ---- Weights (behind the prefetch) ----
    float4 wreg[8];
#pragma unroll
    for (int k = 0; k < 4; ++k) {
        wreg[k]     = W4[4 * lane + k];
        wreg[k + 4] = W4[256 + 4 * lane + k];
    }

    // ---- Phase 0 (wave 0, lanes 0-7): unitaries U = RY * RZ * RX -> sU ----
    // Written and later read ONLY by wave 0: same-wave LDS ordering, no barrier.
    if (tid < LQ * NQ) {
        const int l = tid >> 2, q = tid & 3;
        const float a  = theta[(l * NQ + q) * 3 + 0] * 0.5f;
        const float b  = theta[(l * NQ + q) * 3 + 1] * 0.5f;
        const float cc = theta[(l * NQ + q) * 3 + 2] * 0.5f;
        float sa, ca, sb, cb, sy, cy;
        __sincosf(a,  &sa, &ca);
        __sincosf(b,  &sb, &cb);
        __sincosf(cc, &sy, &cy);
        const float m00r =  ca * cb, m00i = -ca * sb;
        const float m01r = -sa * sb, m01i = -sa * cb;
        const float m10r =  sa * sb, m10i = -sa * cb;
        const float m11r =  ca * cb, m11i =  ca * sb;
        float* u = &sU[tid * 8];
        u[0] = cy * m00r - sy * m10r;  u[1] = cy * m00i - sy * m10i;  // U00
        u[2] = cy * m01r - sy * m11r;  u[3] = cy * m01i - sy * m11i;  // U01
        u[4] = sy * m00r + cy * m10r;  u[5] = sy * m00i + cy * m10i;  // U10
        u[6] = sy * m01r + cy * m11r;  u[7] = sy * m01i + cy * m11i;  // U11
    }

    // ---- Phase 1: encoding matmul over this wave's 16 rows, 4-deep pipeline ----
#pragma unroll
    for (int r = 0; r < RPW; ++r) {
        const int slot = r & 3;
        const float4 x0 = xb[slot][0];
        const float4 x1 = xb[slot][1];
        if (r + 4 < RPW) {
            const size_t rowOff = (size_t)(blockBase + r0 + r + 4) * (DQ / 4);
            xb[slot][0] = in4[rowOff + lane];
            xb[slot][1] = in4[rowOff + lane + 64];
        }

        const float xs[8] = { x0.x, x0.y, x0.z, x0.w, x1.x, x1.y, x1.z, x1.w };
        float4 acc = make_float4(0.f, 0.f, 0.f, 0.f);
#pragma unroll
        for (int k = 0; k < 8; ++k) {
            acc.x += xs[k] * wreg[k].x;
            acc.y += xs[k] * wreg[k].y;
            acc.z += xs[k] * wreg[k].z;
            acc.w += xs[k] * wreg[k].w;
        }
        acc.x = rowsum16(acc.x);
        acc.y = rowsum16(acc.y);
        acc.z = rowsum16(acc.z);
        acc.w = rowsum16(acc.w);
        if ((lane & 15) == 0) sPart[r0 + r][lane >> 4] = acc;
    }

    __syncthreads();          // the ONLY barrier: sPart cross-wave handoff

    // ---- Phase 2 (wave 0 only): lane l = row l. Finish dot in registers,
    //      then the 16-amplitude circuit; no LDS round-trip, no 2nd barrier. ----
    if (tid < RPB) {
        const int row = blockBase + tid;

        const float4 p0 = sPart[tid][0];
        const float4 p1 = sPart[tid][1];
        const float4 p2 = sPart[tid][2];
        const float4 p3 = sPart[tid][3];
        float s0 = p0.x + p1.x + p2.x + p3.x;
        float s1 = p0.y + p1.y + p2.y + p3.y;
        float s2 = p0.z + p1.z + p2.z + p3.z;
        float s3 = p0.w + p1.w + p2.w + p3.w;

        const float4 ph  = *(const float4*)(prev_h + (size_t)row * 4);
        const float4 wt0 = W4[512], wt1 = W4[513], wt2 = W4[514], wt3 = W4[515];
        const float4 bE  = *(const float4*)b_enc;
        s0 += ph.x * wt0.x + ph.y * wt1.x + ph.z * wt2.x + ph.w * wt3.x + bE.x;
        s1 += ph.x * wt0.y + ph.y * wt1.y + ph.z * wt2.y + ph.w * wt3.y + bE.y;
        s2 += ph.x * wt0.z + ph.y * wt1.z + ph.z * wt2.z + ph.w * wt3.z + bE.z;
        s3 += ph.x * wt0.w + ph.y * wt1.w + ph.z * wt2.w + ph.w * wt3.w + bE.w;

        const float kHalfPi = 1.57079632679489662f;
        float cq[4], sq[4];
        __sincosf(fast_tanh(s0) * kHalfPi, &sq[0], &cq[0]);
        __sincosf(fast_tanh(s1) * kHalfPi, &sq[1], &cq[1]);
        __sincosf(fast_tanh(s2) * kHalfPi, &sq[2], &cq[2]);
        __sincosf(fast_tanh(s3) * kHalfPi, &sq[3], &cq[3]);

        float ar[16], ai[16];
#pragma unroll
        for (int j = 0; j < 16; ++j) {
            float v = ((j >> 3) & 1) ? sq[0] : cq[0];
            v      *= ((j >> 2) & 1) ? sq[1] : cq[1];
            v      *= ((j >> 1) & 1) ? sq[2] : cq[2];
            v      *= ((j >> 0) & 1) ? sq[3] : cq[3];
            ar[j] = v;
            ai[j] = 0.f;
        }

#pragma unroll
        for (int l = 0; l < LQ; ++l) {
#pragma unroll
            for (int q = 0; q < NQ; ++q) {
                const float* u = &sU[(l * NQ + q) * 8];
                const float u00r = u[0], u00i = u[1], u01r = u[2], u01i = u[3];
                const float u10r = u[4], u10i = u[5], u11r = u[6], u11i = u[7];
                const int bit = 1 << (3 - q);
#pragma unroll
                for (int j = 0; j < 16; ++j) {
                    if (j & bit) continue;          // compile-time resolved
                    const int k = j | bit;
                    const float a0r = ar[j], a0i = ai[j];
                    const float a1r = ar[k], a1i = ai[k];
                    ar[j] = u00r * a0r - u00i * a0i + u01r * a1r - u01i * a1i;
                    ai[j] = u00r * a0i + u00i * a0r + u01r * a1i + u01i * a1r;
                    ar[k] = u10r * a0r - u10i * a0i + u11r * a1r - u11i * a1i;
                    ai[k] = u10r * a0i + u10i * a0r + u11r * a1i + u11i * a1r;
                }
            }
#pragma unroll
            for (int q = 0; q < NQ - 1; ++q) {      // CNOT chain
                const int cb = 1 << (3 - q), tb = 1 << (2 - q);
#pragma unroll
                for (int j = 0; j < 16; ++j) {
                    if ((j & cb) && !(j & tb)) {    // compile-time resolved
                        const int k = j | tb;
                        float t;
                        t = ar[j]; ar[j] = ar[k]; ar[k] = t;
                        t = ai[j]; ai[j] = ai[k]; ai[k] = t;
                    }
                }
            }
        }

        // PauliZ expectations
        float ev[4] = { 0.f, 0.f, 0.f, 0.f };
#pragma unroll
        for (int j = 0; j < 16; ++j) {
            const float p = ar[j] * ar[j] + ai[j] * ai[j];
#pragma unroll
            for (int q = 0; q < 4; ++q)
                ev[q] += (j & (1 << (3 - q))) ? -p : p;
        }

        // output layer
        float ob[4];
#pragma unroll
        for (int j = 0; j < 4; ++j) {
            float t = b_out[j];
#pragma unroll
            for (int q = 0; q < 4; ++q) t += ev[q] * W_out[q * 4 + j];
            ob[j] = fast_tanh(t);
        }
        *(float4*)(out + (size_t)row * 4) = make_float4(ob[0], ob[1], ob[2], ob[3]);
    }
}

extern "C" void kernel_launch(void* const* d_in, const int* in_sizes, int n_in,
                              void* d_out, int out_size, void* d_ws, size_t ws_size,
                              hipStream_t stream) {
    const float* inputs = (const float*)d_in[0];
    const float* prev_h = (const float*)d_in[1];
    const float* W_enc  = (const float*)d_in[2];
    const float* b_enc  = (const float*)d_in[3];
    const float* theta  = (const float*)d_in[4];
    const float* W_out  = (const float*)d_in[5];
    const float* b_out  = (const float*)d_in[6];
    float* out = (float*)d_out;

    const int B = in_sizes[0] / DQ;                 // 32768
    const int grid = (B + RPB - 1) / RPB;           // 512

    qrnn_kernel<<<grid, BLOCK, 0, stream>>>(inputs, prev_h, W_enc, b_enc, theta,
                                            W_out, b_out, out, B);
}

// Round 7
// 21.552 us; speedup vs baseline: 1.6709x; 1.0209x over previous
//
#include <hip/hip_runtime.h>
#include <math.h>

#define DQ 512          // input feature dim
#define NQ 4            // qubits
#define LQ 2            // layers
#define ROWS_PER_BLOCK 64
#define BLOCK 256

// Sum across the 16-lane DPP "row" group via 4 row_ror steps (pure VALU, no LDS pipe).
// After this every lane holds the sum of its 16-lane group.
__device__ __forceinline__ float rowsum16(float v) {
    int x;
    x = __builtin_amdgcn_update_dpp(0, __float_as_int(v), 0x121, 0xF, 0xF, true); // ror:1
    v += __int_as_float(x);
    x = __builtin_amdgcn_update_dpp(0, __float_as_int(v), 0x122, 0xF, 0xF, true); // ror:2
    v += __int_as_float(x);
    x = __builtin_amdgcn_update_dpp(0, __float_as_int(v), 0x124, 0xF, 0xF, true); // ror:4
    v += __int_as_float(x);
    x = __builtin_amdgcn_update_dpp(0, __float_as_int(v), 0x128, 0xF, 0xF, true); // ror:8
    v += __int_as_float(x);
    return v;
}

__global__ __launch_bounds__(BLOCK) void qrnn_kernel(
    const float* __restrict__ inputs,   // (B,512)
    const float* __restrict__ prev_h,   // (B,4)
    const float* __restrict__ W_enc,    // (516,4)
    const float* __restrict__ b_enc,    // (4)
    const float* __restrict__ theta,    // (2,4,3)
    const float* __restrict__ W_out,    // (4,4)
    const float* __restrict__ b_out,    // (4)
    float* __restrict__ out,            // (B,4)
    int B)
{
    __shared__ float4 sPart[ROWS_PER_BLOCK][5];   // 4 group-partials per row (padded stride)
    __shared__ float  sC[ROWS_PER_BLOCK * 5];     // cos(half-angle) per (row,comp), stride 5
    __shared__ float  sS[ROWS_PER_BLOCK * 5];     // sin(half-angle)
    __shared__ float  sU[LQ * NQ * 8];            // 8 unitaries, 2x2 complex each

    const int tid  = threadIdx.x;
    const int lane = tid & 63;
    const int wave = tid >> 6;
    const int blockBase = blockIdx.x * ROWS_PER_BLOCK;

    // ---------------- Phase 0: shared unitaries U = RY * RZ * RX ----------------
    if (tid < LQ * NQ) {
        const int l = tid >> 2, q = tid & 3;
        const float a  = theta[(l * NQ + q) * 3 + 0] * 0.5f;
        const float b  = theta[(l * NQ + q) * 3 + 1] * 0.5f;
        const float cc = theta[(l * NQ + q) * 3 + 2] * 0.5f;
        float sa, ca, sb, cb, sy, cy;
        sincosf(a,  &sa, &ca);
        sincosf(b,  &sb, &cb);
        sincosf(cc, &sy, &cy);
        const float m00r =  ca * cb, m00i = -ca * sb;
        const float m01r = -sa * sb, m01i = -sa * cb;
        const float m10r =  sa * sb, m10i = -sa * cb;
        const float m11r =  ca * cb, m11i =  ca * sb;
        float* u = &sU[tid * 8];
        u[0] = cy * m00r - sy * m10r;  u[1] = cy * m00i - sy * m10i;  // U00
        u[2] = cy * m01r - sy * m11r;  u[3] = cy * m01i - sy * m11i;  // U01
        u[4] = sy * m00r + cy * m10r;  u[5] = sy * m00i + cy * m10i;  // U10
        u[6] = sy * m01r + cy * m11r;  u[7] = sy * m01i + cy * m11i;  // U11
    }

    // ---------------- Phase 1a: encoding matmul, inputs part ----------------
    const float4* __restrict__ W4 = (const float4*)W_enc;   // W4[d] = W_enc[d][0..3]
    float4 wreg[8];
#pragma unroll
    for (int k = 0; k < 4; ++k) {
        wreg[k]     = W4[4 * lane + k];
        wreg[k + 4] = W4[256 + 4 * lane + k];
    }

    const int r0 = wave * 16;
    const float4* __restrict__ inBase = (const float4*)inputs;

    // 4-deep software pipeline: rows r+1..r+4 in flight while computing row r
    float4 xb[4][2];
#pragma unroll
    for (int p = 0; p < 4; ++p) {
        const float4* in4 = inBase + (size_t)(blockBase + r0 + p) * (DQ / 4);
        xb[p][0] = in4[lane];
        xb[p][1] = in4[lane + 64];
    }

#pragma unroll
    for (int r = 0; r < 16; ++r) {
        const int slot = r & 3;                 // static after full unroll
        const float4 x0 = xb[slot][0];
        const float4 x1 = xb[slot][1];
        if (r + 4 < 16) {
            const float4* in4 = inBase + (size_t)(blockBase + r0 + r + 4) * (DQ / 4);
            xb[slot][0] = in4[lane];
            xb[slot][1] = in4[lane + 64];
        }

        const float xs[8] = { x0.x, x0.y, x0.z, x0.w, x1.x, x1.y, x1.z, x1.w };
        float4 acc = make_float4(0.f, 0.f, 0.f, 0.f);
#pragma unroll
        for (int k = 0; k < 8; ++k) {
            acc.x += xs[k] * wreg[k].x;
            acc.y += xs[k] * wreg[k].y;
            acc.z += xs[k] * wreg[k].z;
            acc.w += xs[k] * wreg[k].w;
        }
        // reduce within each 16-lane group (VALU DPP, no cross-lane LDS traffic)
        acc.x = rowsum16(acc.x);
        acc.y = rowsum16(acc.y);
        acc.z = rowsum16(acc.z);
        acc.w = rowsum16(acc.w);
        if ((lane & 15) == 0) sPart[r0 + r][lane >> 4] = acc;
    }

    __syncthreads();

    // ---------------- Phase 1b: finish dot (4 partials), prev_h, bias, tanh, sincos ----
    // 256 threads: thread -> (row = t>>2, comp = t&3)
    {
        const int row  = tid >> 2;
        const int comp = tid & 3;
        const float* pp = (const float*)&sPart[row][0];
        float s = pp[0 * 4 + comp] + pp[1 * 4 + comp] + pp[2 * 4 + comp] + pp[3 * 4 + comp];

        const float4 ph = *(const float4*)(prev_h + (size_t)(blockBase + row) * 4);
        s += ph.x * W_enc[512 * 4 + comp];
        s += ph.y * W_enc[513 * 4 + comp];
        s += ph.z * W_enc[514 * 4 + comp];
        s += ph.w * W_enc[515 * 4 + comp];
        s += b_enc[comp];

        const float h = tanhf(s) * 1.57079632679489662f;   // half-angle
        float sn, cs;
        __sincosf(h, &sn, &cs);
        sC[row * 5 + comp] = cs;
        sS[row * 5 + comp] = sn;
    }

    __syncthreads();

    // ---------------- Phase 2: per-row 16-amplitude circuit (one thread per row) ------
    if (tid < ROWS_PER_BLOCK) {
        const int row = blockBase + tid;
        float cq[4], sq[4];
#pragma unroll
        for (int j = 0; j < 4; ++j) {
            cq[j] = sC[tid * 5 + j];
            sq[j] = sS[tid * 5 + j];
        }

        float ar[16], ai[16];
#pragma unroll
        for (int j = 0; j < 16; ++j) {
            float v = ((j >> 3) & 1) ? sq[0] : cq[0];
            v      *= ((j >> 2) & 1) ? sq[1] : cq[1];
            v      *= ((j >> 1) & 1) ? sq[2] : cq[2];
            v      *= ((j >> 0) & 1) ? sq[3] : cq[3];
            ar[j] = v;
            ai[j] = 0.f;
        }

#pragma unroll
        for (int l = 0; l < LQ; ++l) {
#pragma unroll
            for (int q = 0; q < NQ; ++q) {
                const float* u = &sU[(l * NQ + q) * 8];
                const float u00r = u[0], u00i = u[1], u01r = u[2], u01i = u[3];
                const float u10r = u[4], u10i = u[5], u11r = u[6], u11i = u[7];
                const int bit = 1 << (3 - q);
#pragma unroll
                for (int j = 0; j < 16; ++j) {
                    if (j & bit) continue;          // compile-time resolved
                    const int k = j | bit;
                    const float a0r = ar[j], a0i = ai[j];
                    const float a1r = ar[k], a1i = ai[k];
                    ar[j] = u00r * a0r - u00i * a0i + u01r * a1r - u01i * a1i;
                    ai[j] = u00r * a0i + u00i * a0r + u01r * a1i + u01i * a1r;
                    ar[k] = u10r * a0r - u10i * a0i + u11r * a1r - u11i * a1i;
                    ai[k] = u10r * a0i + u10i * a0r + u11r * a1i + u11i * a1r;
                }
            }
#pragma unroll
            for (int q = 0; q < NQ - 1; ++q) {      // CNOT chain
                const int cb = 1 << (3 - q), tb = 1 << (2 - q);
#pragma unroll
                for (int j = 0; j < 16; ++j) {
                    if ((j & cb) && !(j & tb)) {    // compile-time resolved
                        const int k = j | tb;
                        float t;
                        t = ar[j]; ar[j] = ar[k]; ar[k] = t;
                        t = ai[j]; ai[j] = ai[k]; ai[k] = t;
                    }
                }
            }
        }

        // PauliZ expectations
        float ev[4] = { 0.f, 0.f, 0.f, 0.f };
#pragma unroll
        for (int j = 0; j < 16; ++j) {
            const float p = ar[j] * ar[j] + ai[j] * ai[j];
#pragma unroll
            for (int q = 0; q < 4; ++q)
                ev[q] += (j & (1 << (3 - q))) ? -p : p;
        }

        // output layer
        float ob[4];
#pragma unroll
        for (int j = 0; j < 4; ++j) {
            float t = b_out[j];
#pragma unroll
            for (int q = 0; q < 4; ++q) t += ev[q] * W_out[q * 4 + j];
            ob[j] = tanhf(t);
        }
        *(float4*)(out + (size_t)row * 4) = make_float4(ob[0], ob[1], ob[2], ob[3]);
    }
}

extern "C" void kernel_launch(void* const* d_in, const int* in_sizes, int n_in,
                              void* d_out, int out_size, void* d_ws, size_t ws_size,
                              hipStream_t stream) {
    const float* inputs = (const float*)d_in[0];
    const float* prev_h = (const float*)d_in[1];
    const float* W_enc  = (const float*)d_in[2];
    const float* b_enc  = (const float*)d_in[3];
    const float* theta  = (const float*)d_in[4];
    const float* W_out  = (const float*)d_in[5];
    const float* b_out  = (const float*)d_in[6];
    float* out = (float*)d_out;

    const int B = in_sizes[0] / DQ;                 // 32768
    const int grid = (B + ROWS_PER_BLOCK - 1) / ROWS_PER_BLOCK;  // 512

    qrnn_kernel<<<grid, BLOCK, 0, stream>>>(inputs, prev_h, W_enc, b_enc, theta,
                                            W_out, b_out, out, B);
}

// Round 8
// 21.418 us; speedup vs baseline: 1.6814x; 1.0063x over previous
//
#include <hip/hip_runtime.h>
#include <math.h>

#define DQ 512          // input feature dim
#define NQ 4            // qubits
#define LQ 2            // layers
#define ROWS_PER_BLOCK 64
#define BLOCK 256

// Sum across the 16-lane DPP "row" group via 4 row_ror steps (pure VALU, no LDS pipe).
// After this every lane holds the sum of its 16-lane group.
__device__ __forceinline__ float rowsum16(float v) {
    int x;
    x = __builtin_amdgcn_update_dpp(0, __float_as_int(v), 0x121, 0xF, 0xF, true); // ror:1
    v += __int_as_float(x);
    x = __builtin_amdgcn_update_dpp(0, __float_as_int(v), 0x122, 0xF, 0xF, true); // ror:2
    v += __int_as_float(x);
    x = __builtin_amdgcn_update_dpp(0, __float_as_int(v), 0x124, 0xF, 0xF, true); // ror:4
    v += __int_as_float(x);
    x = __builtin_amdgcn_update_dpp(0, __float_as_int(v), 0x128, 0xF, 0xF, true); // ror:8
    v += __int_as_float(x);
    return v;
}

__global__ __launch_bounds__(BLOCK) void qrnn_kernel(
    const float* __restrict__ inputs,   // (B,512)
    const float* __restrict__ prev_h,   // (B,4)
    const float* __restrict__ W_enc,    // (516,4)
    const float* __restrict__ b_enc,    // (4)
    const float* __restrict__ theta,    // (2,4,3)
    const float* __restrict__ W_out,    // (4,4)
    const float* __restrict__ b_out,    // (4)
    float* __restrict__ out,            // (B,4)
    int B)
{
    __shared__ float4 sPart[ROWS_PER_BLOCK][5];   // 4 group-partials per row (padded stride)
    __shared__ float  sC[ROWS_PER_BLOCK * 5];     // cos(half-angle) per (row,comp), stride 5
    __shared__ float  sS[ROWS_PER_BLOCK * 5];     // sin(half-angle)
    __shared__ float  sU[LQ * NQ * 8];            // 8 unitaries, 2x2 complex each

    const int tid  = threadIdx.x;
    const int lane = tid & 63;
    const int wave = tid >> 6;
    const int blockBase = blockIdx.x * ROWS_PER_BLOCK;

    // ---------------- Phase 0: shared unitaries U = RY * RZ * RX ----------------
    if (tid < LQ * NQ) {
        const int l = tid >> 2, q = tid & 3;
        const float a  = theta[(l * NQ + q) * 3 + 0] * 0.5f;
        const float b  = theta[(l * NQ + q) * 3 + 1] * 0.5f;
        const float cc = theta[(l * NQ + q) * 3 + 2] * 0.5f;
        float sa, ca, sb, cb, sy, cy;
        sincosf(a,  &sa, &ca);
        sincosf(b,  &sb, &cb);
        sincosf(cc, &sy, &cy);
        const float m00r =  ca * cb, m00i = -ca * sb;
        const float m01r = -sa * sb, m01i = -sa * cb;
        const float m10r =  sa * sb, m10i = -sa * cb;
        const float m11r =  ca * cb, m11i =  ca * sb;
        float* u = &sU[tid * 8];
        u[0] = cy * m00r - sy * m10r;  u[1] = cy * m00i - sy * m10i;  // U00
        u[2] = cy * m01r - sy * m11r;  u[3] = cy * m01i - sy * m11i;  // U01
        u[4] = sy * m00r + cy * m10r;  u[5] = sy * m00i + cy * m10i;  // U10
        u[6] = sy * m01r + cy * m11r;  u[7] = sy * m01i + cy * m11i;  // U11
    }

    // ---------------- Phase 1a: encoding matmul, inputs part ----------------
    const float4* __restrict__ W4 = (const float4*)W_enc;   // W4[d] = W_enc[d][0..3]
    float4 wreg[8];
#pragma unroll
    for (int k = 0; k < 4; ++k) {
        wreg[k]     = W4[4 * lane + k];
        wreg[k + 4] = W4[256 + 4 * lane + k];
    }

    const int r0 = wave * 16;
    const float4* __restrict__ inBase = (const float4*)inputs;

    // 4-deep software pipeline: rows r+1..r+4 in flight while computing row r
    float4 xb[4][2];
#pragma unroll
    for (int p = 0; p < 4; ++p) {
        const float4* in4 = inBase + (size_t)(blockBase + r0 + p) * (DQ / 4);
        xb[p][0] = in4[lane];
        xb[p][1] = in4[lane + 64];
    }

#pragma unroll
    for (int r = 0; r < 16; ++r) {
        const int slot = r & 3;                 // static after full unroll
        const float4 x0 = xb[slot][0];
        const float4 x1 = xb[slot][1];
        if (r + 4 < 16) {
            const float4* in4 = inBase + (size_t)(blockBase + r0 + r + 4) * (DQ / 4);
            xb[slot][0] = in4[lane];
            xb[slot][1] = in4[lane + 64];
        }

        const float xs[8] = { x0.x, x0.y, x0.z, x0.w, x1.x, x1.y, x1.z, x1.w };
        float4 acc = make_float4(0.f, 0.f, 0.f, 0.f);
#pragma unroll
        for (int k = 0; k < 8; ++k) {
            acc.x += xs[k] * wreg[k].x;
            acc.y += xs[k] * wreg[k].y;
            acc.z += xs[k] * wreg[k].z;
            acc.w += xs[k] * wreg[k].w;
        }
        // reduce within each 16-lane group (VALU DPP, no cross-lane LDS traffic)
        acc.x = rowsum16(acc.x);
        acc.y = rowsum16(acc.y);
        acc.z = rowsum16(acc.z);
        acc.w = rowsum16(acc.w);
        if ((lane & 15) == 0) sPart[r0 + r][lane >> 4] = acc;
    }

    __syncthreads();

    // ---------------- Phase 1b: finish dot (4 partials), prev_h, bias, tanh, sincos ----
    // 256 threads: thread -> (row = t>>2, comp = t&3)
    {
        const int row  = tid >> 2;
        const int comp = tid & 3;
        const float* pp = (const float*)&sPart[row][0];
        float s = pp[0 * 4 + comp] + pp[1 * 4 + comp] + pp[2 * 4 + comp] + pp[3 * 4 + comp];

        const float4 ph = *(const float4*)(prev_h + (size_t)(blockBase + row) * 4);
        s += ph.x * W_enc[512 * 4 + comp];
        s += ph.y * W_enc[513 * 4 + comp];
        s += ph.z * W_enc[514 * 4 + comp];
        s += ph.w * W_enc[515 * 4 + comp];
        s += b_enc[comp];

        const float h = tanhf(s) * 1.57079632679489662f;   // half-angle
        float sn, cs;
        __sincosf(h, &sn, &cs);
        sC[row * 5 + comp] = cs;
        sS[row * 5 + comp] = sn;
    }

    __syncthreads();

    // ---------------- Phase 2: per-row 16-amplitude circuit (one thread per row) ------
    if (tid < ROWS_PER_BLOCK) {
        const int row = blockBase + tid;
        float cq[4], sq[4];
#pragma unroll
        for (int j = 0; j < 4; ++j) {
            cq[j] = sC[tid * 5 + j];
            sq[j] = sS[tid * 5 + j];
        }

        float ar[16], ai[16];
#pragma unroll
        for (int j = 0; j < 16; ++j) {
            float v = ((j >> 3) & 1) ? sq[0] : cq[0];
            v      *= ((j >> 2) & 1) ? sq[1] : cq[1];
            v      *= ((j >> 1) & 1) ? sq[2] : cq[2];
            v      *= ((j >> 0) & 1) ? sq[3] : cq[3];
            ar[j] = v;
            ai[j] = 0.f;
        }

#pragma unroll
        for (int l = 0; l < LQ; ++l) {
#pragma unroll
            for (int q = 0; q < NQ; ++q) {
                const float* u = &sU[(l * NQ + q) * 8];
                const float u00r = u[0], u00i = u[1], u01r = u[2], u01i = u[3];
                const float u10r = u[4], u10i = u[5], u11r = u[6], u11i = u[7];
                const int bit = 1 << (3 - q);
#pragma unroll
                for (int j = 0; j < 16; ++j) {
                    if (j & bit) continue;          // compile-time resolved
                    const int k = j | bit;
                    const float a0r = ar[j], a0i = ai[j];
                    const float a1r = ar[k], a1i = ai[k];
                    ar[j] = u00r * a0r - u00i * a0i + u01r * a1r - u01i * a1i;
                    ai[j] = u00r * a0i + u00i * a0r + u01r * a1i + u01i * a1r;
                    ar[k] = u10r * a0r - u10i * a0i + u11r * a1r - u11i * a1i;
                    ai[k] = u10r * a0i + u10i * a0r + u11r * a1i + u11i * a1r;
                }
            }
#pragma unroll
            for (int q = 0; q < NQ - 1; ++q) {      // CNOT chain
                const int cb = 1 << (3 - q), tb = 1 << (2 - q);
#pragma unroll
                for (int j = 0; j < 16; ++j) {
                    if ((j & cb) && !(j & tb)) {    // compile-time resolved
                        const int k = j | tb;
                        float t;
                        t = ar[j]; ar[j] = ar[k]; ar[k] = t;
                        t = ai[j]; ai[j] = ai[k]; ai[k] = t;
                    }
                }
            }
        }

        // PauliZ expectations
        float ev[4] = { 0.f, 0.f, 0.f, 0.f };
#pragma unroll
        for (int j = 0; j < 16; ++j) {
            const float p = ar[j] * ar[j] + ai[j] * ai[j];
#pragma unroll
            for (int q = 0; q < 4; ++q)
                ev[q] += (j & (1 << (3 - q))) ? -p : p;
        }

        // output layer
        float ob[4];
#pragma unroll
        for (int j = 0; j < 4; ++j) {
            float t = b_out[j];
#pragma unroll
            for (int q = 0; q < 4; ++q) t += ev[q] * W_out[q * 4 + j];
            ob[j] = tanhf(t);
        }
        *(float4*)(out + (size_t)row * 4) = make_float4(ob[0], ob[1], ob[2], ob[3]);
    }
}

extern "C" void kernel_launch(void* const* d_in, const int* in_sizes, int n_in,
                              void* d_out, int out_size, void* d_ws, size_t ws_size,
                              hipStream_t stream) {
    const float* inputs = (const float*)d_in[0];
    const float* prev_h = (const float*)d_in[1];
    const float* W_enc  = (const float*)d_in[2];
    const float* b_enc  = (const float*)d_in[3];
    const float* theta  = (const float*)d_in[4];
    const float* W_out  = (const float*)d_in[5];
    const float* b_out  = (const float*)d_in[6];
    float* out = (float*)d_out;

    const int B = in_sizes[0] / DQ;                 // 32768
    const int grid = (B + ROWS_PER_BLOCK - 1) / ROWS_PER_BLOCK;  // 512

    qrnn_kernel<<<grid, BLOCK, 0, stream>>>(inputs, prev_h, W_enc, b_enc, theta,
                                            W_out, b_out, out, B);
}